// Round 1
// 510.999 us; speedup vs baseline: 1.0481x; 1.0481x over previous
//
#include <hip/hip_runtime.h>
#include <math.h>

#define SEQ 12
#define NODES 207
#define NFREQ 7  // SEQ/2+1

// ---------------------------------------------------------------------------
// Kernel 1: build per-node circular-convolution taps g[n][d] from the complex
// weight. rfft(ortho) * w -> irfft(ortho) with imag-of-DC/Nyquist discarded
// reduces to: g[d] = (1/12)(wr0 + 2*sum_{k=1..5}(wr_k cos(2pi k d/12)
//                    + wi_k sin(2pi k d/12)) + (-1)^d wr6)
// ---------------------------------------------------------------------------
__global__ void build_taps(const float* __restrict__ w, float* __restrict__ g) {
    int i = blockIdx.x * blockDim.x + threadIdx.x;
    if (i >= NODES * SEQ) return;
    int n = i / SEQ;
    int d = i - n * SEQ;
    const float* wn = w + n * (NFREQ * 2);  // [7][2] re,im
    float acc = wn[0];  // wr0 (imag of DC bin discarded by irfft)
    const float step = 0.52359877559829887308f;  // 2*pi/12
#pragma unroll
    for (int k = 1; k <= 5; ++k) {
        float ang = step * (float)(k * d);
        acc += 2.0f * (wn[2 * k] * __cosf(ang) + wn[2 * k + 1] * __sinf(ang));
    }
    acc += ((d & 1) ? -1.0f : 1.0f) * wn[12];  // Nyquist: wr6 only
    g[i] = acc * (1.0f / 12.0f);
}

// ---------------------------------------------------------------------------
// Kernel 2: streaming. Block = 256 threads = 256 rows (12288 floats, 48 KB
// of traffic each way). Global access is UNIT-STRIDE float4 (the 6.29 TB/s
// copy pattern); the 48B-stride row<->thread redistribution happens in LDS.
//   stage-in : 3x unit-stride b128 loads  -> tile[q]          (coalesced)
//   compute  : tile[3t..3t+2] -> regs, 144 FMA, regs -> tile  (thread-private
//              slots, conflict-free: 3 coprime 8 => each 8-lane b128 phase
//              hits 8 distinct bank groups)
//   stage-out: 3x unit-stride b128 stores from tile           (coalesced)
// LDS = 12,288 B/block -> LDS allows 13 blocks/CU; waves cap at 8 blocks/CU.
// ---------------------------------------------------------------------------
__global__ __launch_bounds__(256) void filter_rows(
    const float* __restrict__ x, const float* __restrict__ g,
    float* __restrict__ out) {
    __shared__ float4 tile[768];  // 256 rows * 3 float4

    const int t = threadIdx.x;
    const size_t qbase = (size_t)blockIdx.x * 768;  // float4 index of block
    const float4* xv = (const float4*)x + qbase;
    float4* ov = (float4*)out + qbase;

    // ---- stage in: unit-stride, 4 KB per wave-instruction ----
#pragma unroll
    for (int k = 0; k < 3; ++k) {
        int q = k * 256 + t;
        tile[q] = xv[q];
    }

    // taps for this row's node (g is 9.9 KB -> L1-resident, negligible HBM)
    const int row = blockIdx.x * 256 + t;
    const int n = row % NODES;
    const float4* gv = (const float4*)(g + n * SEQ);
    float4 ga = gv[0], gb = gv[1], gc = gv[2];
    float gs[SEQ] = {ga.x, ga.y, ga.z, ga.w, gb.x, gb.y, gb.z, gb.w,
                     gc.x, gc.y, gc.z, gc.w};

    __syncthreads();

    // ---- own row from LDS (thread-private slots 3t..3t+2) ----
    float4 a = tile[3 * t + 0];
    float4 b = tile[3 * t + 1];
    float4 c = tile[3 * t + 2];
    float xs[SEQ] = {a.x, a.y, a.z, a.w, b.x, b.y, b.z, b.w,
                     c.x, c.y, c.z, c.w};

    float o[SEQ];
#pragma unroll
    for (int tt = 0; tt < SEQ; ++tt) {
        float s = xs[tt];  // residual
#pragma unroll
        for (int d = 0; d < SEQ; ++d) {
            s = fmaf(gs[d], xs[(tt + d) % SEQ], s);
        }
        o[tt] = s;
    }

    // write back into own slots (no hazard: same thread owns read+write;
    // other threads touch these slots only after the barrier below)
    tile[3 * t + 0] = make_float4(o[0], o[1], o[2], o[3]);
    tile[3 * t + 1] = make_float4(o[4], o[5], o[6], o[7]);
    tile[3 * t + 2] = make_float4(o[8], o[9], o[10], o[11]);

    __syncthreads();

    // ---- stage out: unit-stride, 4 KB per wave-instruction ----
#pragma unroll
    for (int k = 0; k < 3; ++k) {
        int q = k * 256 + t;
        ov[q] = tile[q];
    }
}

extern "C" void kernel_launch(void* const* d_in, const int* in_sizes, int n_in,
                              void* d_out, int out_size, void* d_ws,
                              size_t ws_size, hipStream_t stream) {
    const float* x = (const float*)d_in[0];
    const float* w = (const float*)d_in[1];
    float* out = (float*)d_out;
    float* g = (float*)d_ws;  // 207*12 floats = 9936 B

    // Build taps (tiny).
    build_taps<<<(NODES * SEQ + 255) / 256, 256, 0, stream>>>(w, g);

    // 1024*32*207 = 6,782,976 rows; /256 = 26496 blocks exactly.
    const int rows = 1024 * 32 * NODES;
    filter_rows<<<rows / 256, 256, 0, stream>>>(x, g, out);
}